// Round 1
// 639.531 us; speedup vs baseline: 1.7656x; 1.7656x over previous
//
#include <hip/hip_runtime.h>
#include <hip/hip_bf16.h>

#define N_NODES 50000
#define N_EDGES 1600000
#define IN_H 256
#define NHEAD 4
#define EDGE_H 64
#define N_ET 8

// ---- ws layout (word offsets), total 14,966,496 words = 59.9 MB ----
// counts   int[50000]    @ 0          (zeroed)
// cursor   int[50000]    @ 50000      (zeroed)
// gmax     uint[1]       @ 100000     (zeroed)
// flag     int[1]        @ 100001
// offsets  int[50001]    @ 100064
// hl       f32[200000]   @ 150080
// hr       f32[200000]   @ 350080
// he       f32[32]       @ 550080
// Wt       bf16[32768]   @ 550112    (16384 words)
// csr_src  int[1600000]  @ 566496
// csr_eid  int[1600000]  @ 2166496
// pos_of_e int[1600000]  @ 3766496
// csr_sc   f32[6400000]  @ 5366496
// h        bf16[6400000] @ 11766496  (3200000 words)

typedef __attribute__((ext_vector_type(8))) short bf16x8v;
typedef __attribute__((ext_vector_type(4))) float f32x4;

__device__ __forceinline__ float ldT(const float* p) { return *p; }
__device__ __forceinline__ float ldT(const __hip_bfloat16* p) { return __bfloat162float(*p); }
__device__ __forceinline__ void stT(float* p, float v) { *p = v; }
__device__ __forceinline__ void stT(__hip_bfloat16* p, float v) { *p = __float2bfloat16(v); }

__device__ __forceinline__ short f2bs(float f) {
    __hip_bfloat16 b = __float2bfloat16(f);
    return (short)__builtin_bit_cast(unsigned short, b);
}
__device__ __forceinline__ float bs2f(short s) {
    return __uint_as_float(((unsigned)(unsigned short)s) << 16);
}

__device__ __forceinline__ unsigned enc_f32(float f) {
    unsigned u = __float_as_uint(f);
    return (u & 0x80000000u) ? ~u : (u | 0x80000000u);
}
__device__ __forceinline__ float dec_f32(unsigned u) {
    return __uint_as_float((u & 0x80000000u) ? (u & 0x7fffffffu) : ~u);
}
__device__ __forceinline__ float lrelu(float v) { return v > 0.f ? v : 0.2f * v; }

// dtype detector: fp32 N(0,1) words have exp-field in [64,160]; bf16-packed don't.
__global__ void k_detect(const unsigned* __restrict__ xw, int* __restrict__ flag) {
    int lane = threadIdx.x;   // 64 threads
    int cnt = 0;
    for (int i = lane; i < 1024; i += 64) {
        unsigned e = (xw[i] >> 23) & 255u;
        if (e >= 64u && e <= 160u) cnt++;
    }
    for (int off = 32; off; off >>= 1) cnt += __shfl_xor(cnt, off);
    if (lane == 0) *flag = (cnt > 512) ? 1 : 0;   // 1 = fp32, 0 = bf16
}

// W[256][128] -> Wt[128][256] bf16 (B^T layout for MFMA, contiguous along K)
__global__ __launch_bounds__(256) void k_wt(const void* __restrict__ Wv,
        __hip_bfloat16* __restrict__ Wt, const int* __restrict__ flag) {
    bool f32 = (*flag != 0);
    for (int i = threadIdx.x; i < 128 * 256; i += 256) {
        int c = i >> 8, k = i & 255;
        float v = f32 ? ((const float*)Wv)[k * 128 + c]
                      : __bfloat162float(((const __hip_bfloat16*)Wv)[k * 128 + c]);
        Wt[i] = __float2bfloat16(v);
    }
}

// h = x @ W via mfma_f32_16x16x32_bf16. 4 waves/block, 16 rows/wave, 64 rows/block.
// A frag: lane holds row=lane&15, k=(lane>>4)*8..+8 (16B contiguous).
// B frag: from Wt (=W^T), lane holds col=lane&15, same contiguous k (16B).
// C frag: col=lane&15, row=(lane>>4)*4+reg  [m89-verified layout].
template<typename T>
__device__ __forceinline__ void proj_body(const T* __restrict__ x,
        const __hip_bfloat16* __restrict__ Wt, __hip_bfloat16* __restrict__ h) {
    int wid = threadIdx.x >> 6, lane = threadIdx.x & 63;
    int row0 = blockIdx.x * 64 + wid * 16;
    if (row0 >= N_NODES) return;   // N_NODES % 16 == 0, so active waves are full
    int r = lane & 15;
    int kb = (lane >> 4) * 8;
    const T* xrow = x + (size_t)(row0 + r) * IN_H;
    f32x4 z = {0.f, 0.f, 0.f, 0.f};
    f32x4 acc[8];
#pragma unroll
    for (int t = 0; t < 8; ++t) acc[t] = z;
#pragma unroll
    for (int kk = 0; kk < 8; ++kk) {
        int k0 = kk * 32 + kb;
        bf16x8v a;
        if constexpr (sizeof(T) == 4) {
            float4 lo = *(const float4*)(xrow + k0);
            float4 hi = *(const float4*)(xrow + k0 + 4);
            a[0] = f2bs(lo.x); a[1] = f2bs(lo.y); a[2] = f2bs(lo.z); a[3] = f2bs(lo.w);
            a[4] = f2bs(hi.x); a[5] = f2bs(hi.y); a[6] = f2bs(hi.z); a[7] = f2bs(hi.w);
        } else {
            a = *(const bf16x8v*)(xrow + k0);
        }
#pragma unroll
        for (int t = 0; t < 8; ++t) {
            bf16x8v b = *(const bf16x8v*)(Wt + (t * 16 + r) * 256 + k0);
            acc[t] = __builtin_amdgcn_mfma_f32_16x16x32_bf16(a, b, acc[t], 0, 0, 0);
        }
    }
    int orow = row0 + (lane >> 4) * 4;
#pragma unroll
    for (int t = 0; t < 8; ++t) {
#pragma unroll
        for (int g = 0; g < 4; ++g) {
            float v = acc[t][g];
            if (v != v) v = 0.f;   // reference: where(isnan(h), 0)
            h[(size_t)(orow + g) * 128 + t * 16 + r] = __float2bfloat16(v);
        }
    }
}

__global__ __launch_bounds__(256) void k_proj(const void* __restrict__ xv,
        const __hip_bfloat16* __restrict__ Wt, __hip_bfloat16* __restrict__ h,
        const int* __restrict__ flag) {
    if (*flag) proj_body<float>((const float*)xv, Wt, h);
    else       proj_body<__hip_bfloat16>((const __hip_bfloat16*)xv, Wt, h);
}

// h_e[ty][head] = sum_d ae[head][d] * (emb[ty] @ We)[head*64+d]
template<typename T>
__device__ __forceinline__ void edge_proj_body(const T* __restrict__ emb,
        const T* __restrict__ We, const T* __restrict__ ae, float* __restrict__ h_e) {
    int t = threadIdx.x;          // col 0..255, head = t>>6
    int lane = t & 63;
    float aev_ = ldT(ae + t);
    for (int ty = 0; ty < N_ET; ++ty) {
        float acc = 0.f;
        for (int k = 0; k < EDGE_H; ++k)
            acc += ldT(emb + ty * EDGE_H + k) * ldT(We + k * 256 + t);
        float v = aev_ * acc;
        for (int off = 32; off; off >>= 1) v += __shfl_xor(v, off);
        if (lane == 0) h_e[ty * NHEAD + (t >> 6)] = v;
    }
}

__global__ __launch_bounds__(256) void k_edge_proj(const void* __restrict__ emb,
        const void* __restrict__ We, const void* __restrict__ ae,
        float* __restrict__ h_e, const int* __restrict__ flag) {
    if (*flag) edge_proj_body<float>((const float*)emb, (const float*)We,
                                     (const float*)ae, h_e);
    else       edge_proj_body<__hip_bfloat16>((const __hip_bfloat16*)emb,
                                              (const __hip_bfloat16*)We,
                                              (const __hip_bfloat16*)ae, h_e);
}

// hl/hr: one wave per node; lane holds flat dims {2*lane, 2*lane+1}
template<typename T>
__device__ __forceinline__ void hlr_body(const __hip_bfloat16* __restrict__ h,
        const T* __restrict__ al, const T* __restrict__ ar,
        float* __restrict__ hl, float* __restrict__ hr) {
    int node = (blockIdx.x << 2) + (threadIdx.x >> 6);
    if (node >= N_NODES) return;
    int lane = threadIdx.x & 63;
    const __hip_bfloat16* hp = h + (size_t)node * 128 + lane * 2;
    float v0 = __bfloat162float(hp[0]), v1 = __bfloat162float(hp[1]);
    float pl = ldT(al + lane * 2) * v0 + ldT(al + lane * 2 + 1) * v1;
    float pr = ldT(ar + lane * 2) * v0 + ldT(ar + lane * 2 + 1) * v1;
    for (int off = 8; off; off >>= 1) {   // reduce 16-lane head groups
        pl += __shfl_xor(pl, off);
        pr += __shfl_xor(pr, off);
    }
    if ((lane & 15) == 0) {
        int head = lane >> 4;
        hl[node * 4 + head] = pl;
        hr[node * 4 + head] = pr;
    }
}

__global__ __launch_bounds__(256) void k_hlr(const __hip_bfloat16* __restrict__ h,
        const void* __restrict__ al, const void* __restrict__ ar,
        float* __restrict__ hl, float* __restrict__ hr, const int* __restrict__ flag) {
    if (*flag) hlr_body<float>(h, (const float*)al, (const float*)ar, hl, hr);
    else       hlr_body<__hip_bfloat16>(h, (const __hip_bfloat16*)al,
                                        (const __hip_bfloat16*)ar, hl, hr);
}

__global__ __launch_bounds__(256) void k_count(
        const int* __restrict__ edge, int* __restrict__ counts) {
    int e = blockIdx.x * 256 + threadIdx.x;
    if (e < N_EDGES) atomicAdd(&counts[edge[N_EDGES + e]], 1);
}

__global__ __launch_bounds__(256) void k_scan(
        const int* __restrict__ counts, int* __restrict__ offsets) {
    __shared__ int psum[256];
    int t = threadIdx.x;
    const int CHUNK = 196;
    int start = t * CHUNK;
    int end = min(start + CHUNK, N_NODES);
    int s = 0;
    for (int i = start; i < end; ++i) s += counts[i];
    psum[t] = s;
    __syncthreads();
    for (int off = 1; off < 256; off <<= 1) {
        int v = (t >= off) ? psum[t - off] : 0;
        __syncthreads();
        psum[t] += v;
        __syncthreads();
    }
    int run = (t == 0) ? 0 : psum[t - 1];
    for (int i = start; i < end; ++i) { offsets[i] = run; run += counts[i]; }
    if (t == 255) offsets[N_NODES] = run;
}

// CSR build: csr_src/csr_eid in CSR order, pos_of_e for score scatter
__global__ __launch_bounds__(256) void k_scatter_idx(
        const int* __restrict__ edge, const int* __restrict__ offsets,
        int* __restrict__ cursor, int* __restrict__ csr_src,
        int* __restrict__ csr_eid, int* __restrict__ pos_of_e) {
    int e = blockIdx.x * 256 + threadIdx.x;
    if (e >= N_EDGES) return;
    int s = edge[e];
    int t = edge[N_EDGES + e];
    int pos = offsets[t] + atomicAdd(&cursor[t], 1);
    csr_src[pos] = s;
    csr_eid[pos] = e;
    pos_of_e[e] = pos;
}

// per-edge lrelu scores -> csr_sc (CSR order), plus global max
__global__ __launch_bounds__(256) void k_escore(
        const int* __restrict__ edge, const int* __restrict__ pos_of_e,
        const float* __restrict__ hl, const float* __restrict__ hr,
        const float* __restrict__ he, float* __restrict__ csr_sc,
        unsigned* __restrict__ gmax) {
    int e = blockIdx.x * 256 + threadIdx.x;
    float m = -3.4e38f;
    if (e < N_EDGES) {
        int s = edge[e], t = edge[N_EDGES + e], ty = edge[2 * N_EDGES + e];
        float4 a = *(const float4*)(hl + s * 4);
        float4 b = *(const float4*)(hr + t * 4);
        float4 c = *(const float4*)(he + ty * 4);
        float4 sc;
        sc.x = lrelu(a.x + b.x + c.x);
        sc.y = lrelu(a.y + b.y + c.y);
        sc.z = lrelu(a.z + b.z + c.z);
        sc.w = lrelu(a.w + b.w + c.w);
        int pos = pos_of_e[e];
        *(float4*)(csr_sc + (size_t)pos * 4) = sc;
        m = fmaxf(fmaxf(sc.x, sc.y), fmaxf(sc.z, sc.w));
    }
    for (int off = 32; off; off >>= 1) m = fmaxf(m, __shfl_xor(m, off));
    __shared__ float wm[4];
    if ((threadIdx.x & 63) == 0) wm[threadIdx.x >> 6] = m;
    __syncthreads();
    if (threadIdx.x == 0)
        atomicMax(gmax, enc_f32(fmaxf(fmaxf(wm[0], wm[1]), fmaxf(wm[2], wm[3]))));
}

// one wave per node. pass1: lane-parallel denom over CSR scores (coalesced).
// pass2: 4 edges/iter — quarter-wave (sub) owns an edge, 16 lanes own 8 dims
// each (16B h load), cross-quarter shfl reduce at the end.
template<typename OUTT>
__device__ __forceinline__ void agg_body(
        const int* __restrict__ csr_src, const int* __restrict__ csr_eid,
        const float* __restrict__ csr_sc, const int* __restrict__ offsets,
        const unsigned* __restrict__ gmax, const __hip_bfloat16* __restrict__ h,
        OUTT* __restrict__ out) {
    int node = (blockIdx.x << 2) + (threadIdx.x >> 6);
    if (node >= N_NODES) return;
    int lane = threadIdx.x & 63;
    int beg = offsets[node], end = offsets[node + 1];
    float gm = dec_f32(*gmax);

    // pass 1: denominators
    float d0 = 0.f, d1 = 0.f, d2 = 0.f, d3 = 0.f;
    for (int j = beg + lane; j < end; j += 64) {
        float4 sc = *(const float4*)(csr_sc + (size_t)j * 4);
        d0 += __expf(sc.x - gm); d1 += __expf(sc.y - gm);
        d2 += __expf(sc.z - gm); d3 += __expf(sc.w - gm);
    }
#pragma unroll
    for (int off = 32; off; off >>= 1) {
        d0 += __shfl_xor(d0, off); d1 += __shfl_xor(d1, off);
        d2 += __shfl_xor(d2, off); d3 += __shfl_xor(d3, off);
    }
    float inv0 = 1.f / (d0 + 1e-16f), inv1 = 1.f / (d1 + 1e-16f);
    float inv2 = 1.f / (d2 + 1e-16f), inv3 = 1.f / (d3 + 1e-16f);

    int sub = lane >> 4;          // edge slot within group of 4
    int l16 = lane & 15;          // dim group: flat dims l16*8 .. +8
    int hd  = l16 >> 2;           // head of my dims
    float invd = hd == 0 ? inv0 : hd == 1 ? inv1 : hd == 2 ? inv2 : inv3;
    float inva = l16 == 0 ? inv0 : l16 == 1 ? inv1 : l16 == 2 ? inv2 : inv3;
    OUTT* attn_out = out + (size_t)N_NODES * 128;

    float acc[8] = {0.f, 0.f, 0.f, 0.f, 0.f, 0.f, 0.f, 0.f};
    for (int jg = beg; jg < end; jg += 4) {
        int j = jg + sub;
        bool valid = j < end;
        int jc = valid ? j : end - 1;
        int s = csr_src[jc];
        float4 sc = *(const float4*)(csr_sc + (size_t)jc * 4);
        if (valid && l16 < 4) {    // attn output: lanes 0..3 of each quarter
            float sch = l16 == 0 ? sc.x : l16 == 1 ? sc.y : l16 == 2 ? sc.z : sc.w;
            int e = csr_eid[jc];
            stT(&attn_out[(size_t)e * 4 + l16], __expf(sch - gm) * inva);
        }
        float schd = hd == 0 ? sc.x : hd == 1 ? sc.y : hd == 2 ? sc.z : sc.w;
        float w = valid ? __expf(schd - gm) * invd : 0.f;
        bf16x8v hv = *(const bf16x8v*)(h + (size_t)s * 128 + l16 * 8);
#pragma unroll
        for (int i = 0; i < 8; ++i) acc[i] += bs2f(hv[i]) * w;
    }
#pragma unroll
    for (int i = 0; i < 8; ++i) {
        acc[i] += __shfl_xor(acc[i], 16);
        acc[i] += __shfl_xor(acc[i], 32);
    }
    if (sub == 0) {
#pragma unroll
        for (int i = 0; i < 8; ++i)
            stT(&out[(size_t)node * 128 + l16 * 8 + i], acc[i]);
    }
}

__global__ __launch_bounds__(256) void k_agg(
        const int* __restrict__ csr_src, const int* __restrict__ csr_eid,
        const float* __restrict__ csr_sc, const int* __restrict__ offsets,
        const unsigned* __restrict__ gmax, const __hip_bfloat16* __restrict__ h,
        void* __restrict__ outv, const int* __restrict__ flag) {
    if (*flag) agg_body<float>(csr_src, csr_eid, csr_sc, offsets, gmax, h, (float*)outv);
    else       agg_body<__hip_bfloat16>(csr_src, csr_eid, csr_sc, offsets, gmax, h,
                                        (__hip_bfloat16*)outv);
}

extern "C" void kernel_launch(void* const* d_in, const int* in_sizes, int n_in,
                              void* d_out, int out_size, void* d_ws, size_t ws_size,
                              hipStream_t stream) {
    const int* edge = (const int*)d_in[0];
    const void* x   = d_in[1];
    const void* emb = d_in[2];
    const void* W   = d_in[3];
    const void* We  = d_in[4];
    const void* al  = d_in[5];
    const void* ar  = d_in[6];
    const void* ae  = d_in[7];

    float* ws = (float*)d_ws;
    int* counts   = (int*)ws;                         // 50000
    int* cursor   = counts + 50000;                   // 50000
    unsigned* gmx = (unsigned*)(counts + 100000);     // 1
    int* flag     = counts + 100001;                  // 1
    int* offsets  = counts + 100064;                  // 50001
    float* hl     = ws + 150080;                      // 200000
    float* hr     = ws + 350080;                      // 200000
    float* he     = ws + 550080;                      // 32
    __hip_bfloat16* Wt = (__hip_bfloat16*)(ws + 550112);   // 32768 bf16
    int* csr_src  = (int*)ws + 566496;                // 1600000
    int* csr_eid  = (int*)ws + 2166496;               // 1600000
    int* pos_of_e = (int*)ws + 3766496;               // 1600000
    float* csr_sc = ws + 5366496;                     // 6400000
    __hip_bfloat16* h = (__hip_bfloat16*)(ws + 11766496);  // 6400000 bf16
    // total 14,966,496 words = 59.9 MB

    hipMemsetAsync(ws, 0, (size_t)100064 * 4, stream);   // counts+cursor+gmax+flag

    k_detect<<<1, 64, 0, stream>>>((const unsigned*)x, flag);
    k_wt<<<1, 256, 0, stream>>>(W, Wt, flag);
    k_proj<<<782, 256, 0, stream>>>(x, Wt, h, flag);
    k_edge_proj<<<1, 256, 0, stream>>>(emb, We, ae, he, flag);
    k_hlr<<<12500, 256, 0, stream>>>(h, al, ar, hl, hr, flag);

    k_count<<<6250, 256, 0, stream>>>(edge, counts);
    k_scan<<<1, 256, 0, stream>>>(counts, offsets);
    k_scatter_idx<<<6250, 256, 0, stream>>>(edge, offsets, cursor,
                                            csr_src, csr_eid, pos_of_e);
    k_escore<<<6250, 256, 0, stream>>>(edge, pos_of_e, hl, hr, he, csr_sc, gmx);

    k_agg<<<12500, 256, 0, stream>>>(csr_src, csr_eid, csr_sc, offsets,
                                     gmx, h, d_out, flag);
}

// Round 2
// 536.240 us; speedup vs baseline: 2.1057x; 1.1926x over previous
//
#include <hip/hip_runtime.h>
#include <hip/hip_bf16.h>

#define N_NODES 50000
#define N_EDGES 1600000
#define IN_H 256
#define NHEAD 4
#define EDGE_H 64
#define N_ET 8

// ---- ws layout (word offsets), total 16,566,496 words = 66.3 MB ----
// counts   int[50000]     @ 0          (zeroed)
// cursor   int[50000]     @ 50000      (zeroed)
// gmax     uint[1]        @ 100000     (zeroed)
// flag     int[1]         @ 100001
// offsets  int[50001]     @ 100064
// hl       f32[200000]    @ 150080
// hr       f32[200000]    @ 350080
// he       f32[32]        @ 550080
// Wt       bf16[32768]    @ 550112    (16384 words)
// rec      f32[12800000]  @ 566496    (32B/edge: sc0..3, s, e, pad, pad)
// h        bf16[6400000]  @ 13366496  (3200000 words)

typedef __attribute__((ext_vector_type(8))) short bf16x8v;
typedef __attribute__((ext_vector_type(4))) float f32x4;

__device__ __forceinline__ float ldT(const float* p) { return *p; }
__device__ __forceinline__ float ldT(const __hip_bfloat16* p) { return __bfloat162float(*p); }
__device__ __forceinline__ void stT(float* p, float v) { *p = v; }
__device__ __forceinline__ void stT(__hip_bfloat16* p, float v) { *p = __float2bfloat16(v); }

__device__ __forceinline__ short f2bs(float f) {
    __hip_bfloat16 b = __float2bfloat16(f);
    return (short)__builtin_bit_cast(unsigned short, b);
}
__device__ __forceinline__ float bs2f(short s) {
    return __uint_as_float(((unsigned)(unsigned short)s) << 16);
}

__device__ __forceinline__ unsigned enc_f32(float f) {
    unsigned u = __float_as_uint(f);
    return (u & 0x80000000u) ? ~u : (u | 0x80000000u);
}
__device__ __forceinline__ float dec_f32(unsigned u) {
    return __uint_as_float((u & 0x80000000u) ? (u & 0x7fffffffu) : ~u);
}
__device__ __forceinline__ float lrelu(float v) { return v > 0.f ? v : 0.2f * v; }

// dtype detector: fp32 N(0,1) words have exp-field in [64,160]; bf16-packed don't.
__global__ void k_detect(const unsigned* __restrict__ xw, int* __restrict__ flag) {
    int lane = threadIdx.x;   // 64 threads
    int cnt = 0;
    for (int i = lane; i < 1024; i += 64) {
        unsigned e = (xw[i] >> 23) & 255u;
        if (e >= 64u && e <= 160u) cnt++;
    }
    for (int off = 32; off; off >>= 1) cnt += __shfl_xor(cnt, off);
    if (lane == 0) *flag = (cnt > 512) ? 1 : 0;   // 1 = fp32, 0 = bf16
}

// W[256][128] -> Wt[128][256] bf16 (B^T layout for MFMA, contiguous along K)
__global__ __launch_bounds__(256) void k_wt(const void* __restrict__ Wv,
        __hip_bfloat16* __restrict__ Wt, const int* __restrict__ flag) {
    bool f32 = (*flag != 0);
    for (int i = threadIdx.x; i < 128 * 256; i += 256) {
        int c = i >> 8, k = i & 255;
        float v = f32 ? ((const float*)Wv)[k * 128 + c]
                      : __bfloat162float(((const __hip_bfloat16*)Wv)[k * 128 + c]);
        Wt[i] = __float2bfloat16(v);
    }
}

// h = x @ W via mfma_f32_16x16x32_bf16. 4 waves/block, 16 rows/wave, 64 rows/block.
// Also absorbs the per-target edge count (2048 edges/block, atomics hide
// under the MFMA work).
template<typename T>
__device__ __forceinline__ void proj_body(const T* __restrict__ x,
        const __hip_bfloat16* __restrict__ Wt, __hip_bfloat16* __restrict__ h) {
    int wid = threadIdx.x >> 6, lane = threadIdx.x & 63;
    int row0 = blockIdx.x * 64 + wid * 16;
    if (row0 >= N_NODES) return;   // N_NODES % 16 == 0, so active waves are full
    int r = lane & 15;
    int kb = (lane >> 4) * 8;
    const T* xrow = x + (size_t)(row0 + r) * IN_H;
    f32x4 z = {0.f, 0.f, 0.f, 0.f};
    f32x4 acc[8];
#pragma unroll
    for (int t = 0; t < 8; ++t) acc[t] = z;
#pragma unroll
    for (int kk = 0; kk < 8; ++kk) {
        int k0 = kk * 32 + kb;
        bf16x8v a;
        if constexpr (sizeof(T) == 4) {
            float4 lo = *(const float4*)(xrow + k0);
            float4 hi = *(const float4*)(xrow + k0 + 4);
            a[0] = f2bs(lo.x); a[1] = f2bs(lo.y); a[2] = f2bs(lo.z); a[3] = f2bs(lo.w);
            a[4] = f2bs(hi.x); a[5] = f2bs(hi.y); a[6] = f2bs(hi.z); a[7] = f2bs(hi.w);
        } else {
            a = *(const bf16x8v*)(xrow + k0);
        }
#pragma unroll
        for (int t = 0; t < 8; ++t) {
            bf16x8v b = *(const bf16x8v*)(Wt + (t * 16 + r) * 256 + k0);
            acc[t] = __builtin_amdgcn_mfma_f32_16x16x32_bf16(a, b, acc[t], 0, 0, 0);
        }
    }
    int orow = row0 + (lane >> 4) * 4;
#pragma unroll
    for (int t = 0; t < 8; ++t) {
#pragma unroll
        for (int g = 0; g < 4; ++g) {
            float v = acc[t][g];
            if (v != v) v = 0.f;   // reference: where(isnan(h), 0)
            h[(size_t)(orow + g) * 128 + t * 16 + r] = __float2bfloat16(v);
        }
    }
}

__global__ __launch_bounds__(256) void k_proj(const void* __restrict__ xv,
        const __hip_bfloat16* __restrict__ Wt, __hip_bfloat16* __restrict__ h,
        const int* __restrict__ edge, int* __restrict__ counts,
        const int* __restrict__ flag) {
    // folded k_count: fire-and-forget atomics overlap the MFMA work below
    {
        int base = blockIdx.x * 2048;
        int lim = min(base + 2048, N_EDGES);
        for (int i = base + threadIdx.x; i < lim; i += 256)
            atomicAdd(&counts[edge[N_EDGES + i]], 1);
    }
    if (*flag) proj_body<float>((const float*)xv, Wt, h);
    else       proj_body<__hip_bfloat16>((const __hip_bfloat16*)xv, Wt, h);
}

// h_e[ty][head] = sum_d ae[head][d] * (emb[ty] @ We)[head*64+d]
template<typename T>
__device__ __forceinline__ void edge_proj_body(const T* __restrict__ emb,
        const T* __restrict__ We, const T* __restrict__ ae, float* __restrict__ h_e) {
    int t = threadIdx.x;          // col 0..255, head = t>>6
    int lane = t & 63;
    float aev_ = ldT(ae + t);
    for (int ty = 0; ty < N_ET; ++ty) {
        float acc = 0.f;
        for (int k = 0; k < EDGE_H; ++k)
            acc += ldT(emb + ty * EDGE_H + k) * ldT(We + k * 256 + t);
        float v = aev_ * acc;
        for (int off = 32; off; off >>= 1) v += __shfl_xor(v, off);
        if (lane == 0) h_e[ty * NHEAD + (t >> 6)] = v;
    }
}

__global__ __launch_bounds__(256) void k_edge_proj(const void* __restrict__ emb,
        const void* __restrict__ We, const void* __restrict__ ae,
        float* __restrict__ h_e, const int* __restrict__ flag) {
    if (*flag) edge_proj_body<float>((const float*)emb, (const float*)We,
                                     (const float*)ae, h_e);
    else       edge_proj_body<__hip_bfloat16>((const __hip_bfloat16*)emb,
                                              (const __hip_bfloat16*)We,
                                              (const __hip_bfloat16*)ae, h_e);
}

// hl/hr: one wave per node; lane holds flat dims {2*lane, 2*lane+1}
template<typename T>
__device__ __forceinline__ void hlr_body(const __hip_bfloat16* __restrict__ h,
        const T* __restrict__ al, const T* __restrict__ ar,
        float* __restrict__ hl, float* __restrict__ hr) {
    int node = (blockIdx.x << 2) + (threadIdx.x >> 6);
    if (node >= N_NODES) return;
    int lane = threadIdx.x & 63;
    const __hip_bfloat16* hp = h + (size_t)node * 128 + lane * 2;
    float v0 = __bfloat162float(hp[0]), v1 = __bfloat162float(hp[1]);
    float pl = ldT(al + lane * 2) * v0 + ldT(al + lane * 2 + 1) * v1;
    float pr = ldT(ar + lane * 2) * v0 + ldT(ar + lane * 2 + 1) * v1;
    for (int off = 8; off; off >>= 1) {   // reduce 16-lane head groups
        pl += __shfl_xor(pl, off);
        pr += __shfl_xor(pr, off);
    }
    if ((lane & 15) == 0) {
        int head = lane >> 4;
        hl[node * 4 + head] = pl;
        hr[node * 4 + head] = pr;
    }
}

__global__ __launch_bounds__(256) void k_hlr(const __hip_bfloat16* __restrict__ h,
        const void* __restrict__ al, const void* __restrict__ ar,
        float* __restrict__ hl, float* __restrict__ hr, const int* __restrict__ flag) {
    if (*flag) hlr_body<float>(h, (const float*)al, (const float*)ar, hl, hr);
    else       hlr_body<__hip_bfloat16>(h, (const __hip_bfloat16*)al,
                                        (const __hip_bfloat16*)ar, hl, hr);
}

__global__ __launch_bounds__(256) void k_scan(
        const int* __restrict__ counts, int* __restrict__ offsets) {
    __shared__ int psum[256];
    int t = threadIdx.x;
    const int CHUNK = 196;
    int start = t * CHUNK;
    int end = min(start + CHUNK, N_NODES);
    int s = 0;
    for (int i = start; i < end; ++i) s += counts[i];
    psum[t] = s;
    __syncthreads();
    for (int off = 1; off < 256; off <<= 1) {
        int v = (t >= off) ? psum[t - off] : 0;
        __syncthreads();
        psum[t] += v;
        __syncthreads();
    }
    int run = (t == 0) ? 0 : psum[t - 1];
    for (int i = start; i < end; ++i) { offsets[i] = run; run += counts[i]; }
    if (t == 255) offsets[N_NODES] = run;
}

// CSR build + scores in one pass. Per edge: one 32B record
// {sc0,sc1,sc2,sc3, s, e, pad, pad} written as two 16B stores to the SAME
// 64B line -> 1 dirty line/edge (was ~3 across scatter_idx+escore).
__global__ __launch_bounds__(256) void k_build(
        const int* __restrict__ edge, const int* __restrict__ offsets,
        int* __restrict__ cursor,
        const float* __restrict__ hl, const float* __restrict__ hr,
        const float* __restrict__ he,
        float* __restrict__ rec, unsigned* __restrict__ gmax) {
    int e = blockIdx.x * 256 + threadIdx.x;   // 6250*256 == N_EDGES exactly
    int s = edge[e], t = edge[N_EDGES + e], ty = edge[2 * N_EDGES + e];
    int pos = offsets[t] + atomicAdd(&cursor[t], 1);
    float4 a = *(const float4*)(hl + s * 4);
    float4 b = *(const float4*)(hr + t * 4);
    float4 c = *(const float4*)(he + ty * 4);
    float4 sc;
    sc.x = lrelu(a.x + b.x + c.x);
    sc.y = lrelu(a.y + b.y + c.y);
    sc.z = lrelu(a.z + b.z + c.z);
    sc.w = lrelu(a.w + b.w + c.w);
    float4 se;
    se.x = __int_as_float(s); se.y = __int_as_float(e); se.z = 0.f; se.w = 0.f;
    float* rp = rec + (size_t)pos * 8;
    *(float4*)rp = sc;
    *(float4*)(rp + 4) = se;
    float m = fmaxf(fmaxf(sc.x, sc.y), fmaxf(sc.z, sc.w));
    for (int off = 32; off; off >>= 1) m = fmaxf(m, __shfl_xor(m, off));
    __shared__ float wm[4];
    if ((threadIdx.x & 63) == 0) wm[threadIdx.x >> 6] = m;
    __syncthreads();
    if (threadIdx.x == 0)
        atomicMax(gmax, enc_f32(fmaxf(fmaxf(wm[0], wm[1]), fmaxf(wm[2], wm[3]))));
}

// one wave per node. pass1: lane-parallel denom over rec scores (stride-32B,
// coalesced, L3-hot). pass2: 4 edges/iter — quarter-wave owns an edge,
// 16 lanes own 8 dims each (16B h load), cross-quarter shfl reduce at end.
template<typename OUTT>
__device__ __forceinline__ void agg_body(
        const float* __restrict__ rec, const int* __restrict__ offsets,
        const unsigned* __restrict__ gmax, const __hip_bfloat16* __restrict__ h,
        OUTT* __restrict__ out) {
    int node = (blockIdx.x << 2) + (threadIdx.x >> 6);
    if (node >= N_NODES) return;
    int lane = threadIdx.x & 63;
    int beg = offsets[node], end = offsets[node + 1];
    float gm = dec_f32(*gmax);

    // pass 1: denominators
    float d0 = 0.f, d1 = 0.f, d2 = 0.f, d3 = 0.f;
    for (int j = beg + lane; j < end; j += 64) {
        float4 sc = *(const float4*)(rec + (size_t)j * 8);
        d0 += __expf(sc.x - gm); d1 += __expf(sc.y - gm);
        d2 += __expf(sc.z - gm); d3 += __expf(sc.w - gm);
    }
#pragma unroll
    for (int off = 32; off; off >>= 1) {
        d0 += __shfl_xor(d0, off); d1 += __shfl_xor(d1, off);
        d2 += __shfl_xor(d2, off); d3 += __shfl_xor(d3, off);
    }
    float inv0 = 1.f / (d0 + 1e-16f), inv1 = 1.f / (d1 + 1e-16f);
    float inv2 = 1.f / (d2 + 1e-16f), inv3 = 1.f / (d3 + 1e-16f);

    int sub = lane >> 4;          // edge slot within group of 4
    int l16 = lane & 15;          // dim group: flat dims l16*8 .. +8
    int hd  = l16 >> 2;           // head of my dims
    float invd = hd == 0 ? inv0 : hd == 1 ? inv1 : hd == 2 ? inv2 : inv3;
    float inva = l16 == 0 ? inv0 : l16 == 1 ? inv1 : l16 == 2 ? inv2 : inv3;
    OUTT* attn_out = out + (size_t)N_NODES * 128;

    float acc[8] = {0.f, 0.f, 0.f, 0.f, 0.f, 0.f, 0.f, 0.f};
    for (int jg = beg; jg < end; jg += 4) {
        int j = jg + sub;
        bool valid = j < end;
        int jc = valid ? j : end - 1;
        const float* rp = rec + (size_t)jc * 8;
        float4 sc = *(const float4*)rp;
        int2 se = *(const int2*)(rp + 4);
        int s = se.x;
        if (valid && l16 < 4) {    // attn output: lanes 0..3 of each quarter
            float sch = l16 == 0 ? sc.x : l16 == 1 ? sc.y : l16 == 2 ? sc.z : sc.w;
            stT(&attn_out[(size_t)se.y * 4 + l16], __expf(sch - gm) * inva);
        }
        float schd = hd == 0 ? sc.x : hd == 1 ? sc.y : hd == 2 ? sc.z : sc.w;
        float w = valid ? __expf(schd - gm) * invd : 0.f;
        bf16x8v hv = *(const bf16x8v*)(h + (size_t)s * 128 + l16 * 8);
#pragma unroll
        for (int i = 0; i < 8; ++i) acc[i] += bs2f(hv[i]) * w;
    }
#pragma unroll
    for (int i = 0; i < 8; ++i) {
        acc[i] += __shfl_xor(acc[i], 16);
        acc[i] += __shfl_xor(acc[i], 32);
    }
    if (sub == 0) {
#pragma unroll
        for (int i = 0; i < 8; ++i)
            stT(&out[(size_t)node * 128 + l16 * 8 + i], acc[i]);
    }
}

__global__ __launch_bounds__(256) void k_agg(
        const float* __restrict__ rec, const int* __restrict__ offsets,
        const unsigned* __restrict__ gmax, const __hip_bfloat16* __restrict__ h,
        void* __restrict__ outv, const int* __restrict__ flag) {
    if (*flag) agg_body<float>(rec, offsets, gmax, h, (float*)outv);
    else       agg_body<__hip_bfloat16>(rec, offsets, gmax, h, (__hip_bfloat16*)outv);
}

extern "C" void kernel_launch(void* const* d_in, const int* in_sizes, int n_in,
                              void* d_out, int out_size, void* d_ws, size_t ws_size,
                              hipStream_t stream) {
    const int* edge = (const int*)d_in[0];
    const void* x   = d_in[1];
    const void* emb = d_in[2];
    const void* W   = d_in[3];
    const void* We  = d_in[4];
    const void* al  = d_in[5];
    const void* ar  = d_in[6];
    const void* ae  = d_in[7];

    float* ws = (float*)d_ws;
    int* counts   = (int*)ws;                         // 50000
    int* cursor   = counts + 50000;                   // 50000
    unsigned* gmx = (unsigned*)(counts + 100000);     // 1
    int* flag     = counts + 100001;                  // 1
    int* offsets  = counts + 100064;                  // 50001
    float* hl     = ws + 150080;                      // 200000
    float* hr     = ws + 350080;                      // 200000
    float* he     = ws + 550080;                      // 32
    __hip_bfloat16* Wt = (__hip_bfloat16*)(ws + 550112);   // 32768 bf16
    float* rec    = ws + 566496;                      // 12,800,000 (32B-aligned)
    __hip_bfloat16* h = (__hip_bfloat16*)(ws + 13366496);  // 6,400,000 bf16
    // total 16,566,496 words = 66.3 MB

    hipMemsetAsync(ws, 0, (size_t)100064 * 4, stream);   // counts+cursor+gmax+flag

    k_detect<<<1, 64, 0, stream>>>((const unsigned*)x, flag);
    k_wt<<<1, 256, 0, stream>>>(W, Wt, flag);
    k_proj<<<782, 256, 0, stream>>>(x, Wt, h, edge, counts, flag);
    k_edge_proj<<<1, 256, 0, stream>>>(emb, We, ae, he, flag);
    k_hlr<<<12500, 256, 0, stream>>>(h, al, ar, hl, hr, flag);

    k_scan<<<1, 256, 0, stream>>>(counts, offsets);
    k_build<<<6250, 256, 0, stream>>>(edge, offsets, cursor, hl, hr, he, rec, gmx);

    k_agg<<<12500, 256, 0, stream>>>(rec, offsets, gmx, h, d_out, flag);
}